// Round 16
// baseline (302.831 us; speedup 1.0000x reference)
//
#include <hip/hip_runtime.h>
#include <hip/hip_bf16.h>
#include <cstdint>
#include <cstddef>

typedef float  f32x4  __attribute__((ext_vector_type(4)));
typedef __bf16 bf16x8 __attribute__((ext_vector_type(8)));
typedef __bf16 bf16x4 __attribute__((ext_vector_type(4)));

#define N_TOK  8192
#define INDIM  1024
#define DMODEL 512
#define NHALF  4096   // key-split half for P materialization

__device__ __forceinline__ f32x4 mfma16x16x32(bf16x8 a, bf16x8 b, f32x4 c){
  return __builtin_amdgcn_mfma_f32_16x16x32_bf16(a, b, c, 0, 0, 0);
}

__device__ __forceinline__ void async_copy16(void* lds, const void* g){
  __builtin_amdgcn_global_load_lds((__attribute__((address_space(1))) void*)g,
                                   (__attribute__((address_space(3))) void*)lds,
                                   16, 0, 0);
}

// ---------------- convert / transpose / bias-concat ----------------
__global__ void k_cvt(const float* __restrict__ in, __bf16* __restrict__ out, int n4){
  int stride = gridDim.x * blockDim.x;
  for (int i = blockIdx.x * blockDim.x + threadIdx.x; i < n4; i += stride){
    f32x4 v = ((const f32x4*)in)[i];
    bf16x4 o;
    o[0]=(__bf16)v[0]; o[1]=(__bf16)v[1]; o[2]=(__bf16)v[2]; o[3]=(__bf16)v[3];
    ((bf16x4*)out)[i] = o;
  }
}

__global__ void k_tcvt(const float* __restrict__ W, __bf16* __restrict__ Wt, int Kd, int Nd){
  int total = Kd * Nd;
  int stride = gridDim.x * blockDim.x;
  for (int i = blockIdx.x * blockDim.x + threadIdx.x; i < total; i += stride){
    int k = i / Nd, n = i - k * Nd;
    Wt[(size_t)n * Kd + k] = (__bf16)W[i];
  }
}

__global__ void k_bias2(const float* __restrict__ a, const float* __restrict__ b,
                        float* __restrict__ o){
  int idx = blockIdx.x * 256 + threadIdx.x;   // 0..1023
  o[idx] = (idx < 512) ? a[idx] : b[idx - 512];
}

// ---------------- generalized GEMM: C[M,N] = A[M,K-chunk] @ Bt^T ------------
// m97 fragments + depth-2 software pipeline: TRIPLE-buffered LDS, stage(t+2)
// issued at top of iter t, counted s_waitcnt vmcnt(8/4/0) + raw s_barrier
// (no forced vmcnt(0) drain mid-loop -> ~2 iterations of latency cover).
// EPI: 0 = +bias[col]; 2 = exp(scale*acc); 3 = plain.
// MAP: 0 = (x=m, y=n, z=K-chunk); 1 = xcd-chunked m, n inner (grid 2048);
//      2 = z = xcd>>2, n innermost (grid 512).
// RSUM: fused per-(colblock,row) partial row sums from acc (deterministic).
template<int EPI, int MAP, int RSUM>
__global__ __launch_bounds__(256) void k_gemm(
    const __bf16* __restrict__ A, const __bf16* __restrict__ Bt,
    const float* __restrict__ bias, __bf16* __restrict__ C,
    int M, int N, int K, int lda, int ldb, int ldc, float scale,
    float* __restrict__ rsp, int rbase)
{
  __shared__ __bf16 Als[3][128][32];
  __shared__ __bf16 Bls[3][128][32];
  const int tid = threadIdx.x;
  const int w = tid >> 6, l = tid & 63;
  const int lr = l & 15, lg = l >> 4;
  const int wr = w >> 1, wc = w & 1;
  int m0, n0, kz, zsel;
  if (MAP == 0){
    m0 = blockIdx.x * 128; n0 = blockIdx.y * 128; zsel = blockIdx.z; kz = zsel * K;
  } else if (MAP == 1){
    int lin = blockIdx.x, xcd = lin & 7, idx = lin >> 3;
    m0 = (xcd*8 + (idx & 7)) * 128; n0 = (idx >> 3) * 128; zsel = 0; kz = 0;
  } else {
    int lin = blockIdx.x, xcd = lin & 7, i = lin >> 3;
    zsel = xcd >> 2; kz = zsel * K;
    m0 = ((xcd & 3)*16 + (i >> 2)) * 128; n0 = (i & 3) * 128;
  }
  const int srow = l >> 2;
  const int skof = (l & 3) * 8;

  auto stage = [&](int b, int kk){
    #pragma unroll
    for (int i = 0; i < 2; ++i){
      int c = i * 4 + w;
      async_copy16((char*)&Als[b][0][0] + c * 1024,
                   A  + (size_t)(m0 + c*16 + srow) * lda + kk + skof);
      async_copy16((char*)&Bls[b][0][0] + c * 1024,
                   Bt + (size_t)(n0 + c*16 + srow) * ldb + kk + skof);
    }
  };

  f32x4 acc[4][4] = {};
  const int nt = K >> 5;      // >= 16 for all our shapes
  stage(0, kz);
  stage(1, kz + 32);
  for (int t = 0; t < nt; ++t){
    const int cur = t % 3;
    if (t + 2 < nt) stage((t + 2) % 3, kz + (t+2)*32);   // depth-2 prefetch
    __builtin_amdgcn_sched_barrier(0);
    if (t + 2 < nt)      { asm volatile("s_waitcnt vmcnt(8)" ::: "memory"); }
    else if (t + 1 < nt) { asm volatile("s_waitcnt vmcnt(4)" ::: "memory"); }
    else                 { asm volatile("s_waitcnt vmcnt(0)" ::: "memory"); }
    __builtin_amdgcn_sched_barrier(0);
    __builtin_amdgcn_s_barrier();    // buf[cur] complete for all waves
    __builtin_amdgcn_sched_barrier(0);
    bf16x8 af[4], bfv[4];
    #pragma unroll
    for (int mf = 0; mf < 4; ++mf) af[mf]  = *(const bf16x8*)&Als[cur][wr*64 + mf*16 + lr][lg*8];
    #pragma unroll
    for (int nf = 0; nf < 4; ++nf) bfv[nf] = *(const bf16x8*)&Bls[cur][wc*64 + nf*16 + lr][lg*8];
    #pragma unroll
    for (int mf = 0; mf < 4; ++mf)
      #pragma unroll
      for (int nf = 0; nf < 4; ++nf)
        acc[mf][nf] = mfma16x16x32(af[mf], bfv[nf], acc[mf][nf]);
    __builtin_amdgcn_sched_barrier(0);
    __builtin_amdgcn_s_barrier();    // all waves done reading buf[cur]
  }
  // ---- epilogue: direct scattered stores + optional fused row sums ----
  __bf16* Cd = C + (size_t)zsel * (size_t)M * ldc;
  float rsp4[4][4];
  #pragma unroll
  for (int mf = 0; mf < 4; ++mf)
    #pragma unroll
    for (int r = 0; r < 4; ++r) rsp4[mf][r] = 0.0f;
  #pragma unroll
  for (int mf = 0; mf < 4; ++mf)
    #pragma unroll
    for (int nf = 0; nf < 4; ++nf)
      #pragma unroll
      for (int r = 0; r < 4; ++r){
        int row = m0 + wr*64 + mf*16 + lg*4 + r;
        int col = n0 + wc*64 + nf*16 + lr;
        float v = acc[mf][nf][r];
        if (EPI == 0) v += bias[col];
        if (EPI == 2) v = __expf(v * scale);
        Cd[(size_t)row * ldc + col] = (__bf16)v;
        if (RSUM) rsp4[mf][r] += v;
      }
  if (RSUM){
    #pragma unroll
    for (int mf = 0; mf < 4; ++mf)
      #pragma unroll
      for (int r = 0; r < 4; ++r)
        #pragma unroll
        for (int dl = 1; dl < 16; dl <<= 1)
          rsp4[mf][r] += __shfl_xor(rsp4[mf][r], dl);
    if (lr == 0){
      int cb = rbase + (n0 >> 6) + wc;
      #pragma unroll
      for (int mf = 0; mf < 4; ++mf)
        #pragma unroll
        for (int r = 0; r < 4; ++r)
          rsp[(size_t)cb * N_TOK + m0 + wr*64 + mf*16 + lg*4 + r] = rsp4[mf][r];
    }
  }
}

// ---------------- rs[row] = sum of 128 rsp partials ----------------
__global__ __launch_bounds__(256) void k_rsum(
    const float* __restrict__ rsp, float* __restrict__ rs)
{
  int row = blockIdx.x * 256 + threadIdx.x;   // 8192
  float s = 0.0f;
  #pragma unroll 8
  for (int j = 0; j < 128; ++j) s += rsp[(size_t)j * N_TOK + row];
  rs[row] = s;
}

// ---------------- V-projection split-K combine: vtb = p0 + p1 + bv[row] -----
__global__ __launch_bounds__(256) void k_vcomb(
    const __bf16* __restrict__ p, const float* __restrict__ bv,
    __bf16* __restrict__ vtb)
{
  int idx = blockIdx.x * 256 + threadIdx.x;   // 512*8192/8
  int row = idx >> 10;
  float b = bv[row];
  bf16x8 a = ((const bf16x8*)p)[idx];
  bf16x8 c = ((const bf16x8*)(p + (size_t)DMODEL * N_TOK))[idx];
  bf16x8 o;
  #pragma unroll
  for (int i = 0; i < 8; ++i)
    o[i] = (__bf16)((float)a[i] + (float)c[i] + b);
  ((bf16x8*)vtb)[idx] = o;
}

// ---------------- MLP head (fused 4-partial combine + GEMM + reduce) --------
__global__ __launch_bounds__(256) void k_mlp(
    const __bf16* __restrict__ p00, const __bf16* __restrict__ p01,
    const __bf16* __restrict__ p10, const __bf16* __restrict__ p11,
    const float* __restrict__ rs, const __bf16* __restrict__ W1t,
    const float* __restrict__ b1, const float* __restrict__ W2,
    const float* __restrict__ b2, float* __restrict__ out)
{
  __shared__ __bf16 Als[64][512];
  __shared__ float  red[4][64];
  const int tid = threadIdx.x;
  const int w = tid >> 6, l = tid & 63;
  const int lr = l & 15, lg = l >> 4;
  const int m0 = blockIdx.x * 64;
  #pragma unroll
  for (int i = 0; i < 16; ++i){
    int chunk = i*256 + tid;            // 0..4095
    int rl = chunk >> 6, c8 = chunk & 63;
    size_t off = (size_t)(m0 + rl) * 64 + c8;
    float inv = 1.0f / rs[m0 + rl];
    bf16x8 a = ((const bf16x8*)p00)[off];
    bf16x8 b = ((const bf16x8*)p01)[off];
    bf16x8 c = ((const bf16x8*)p10)[off];
    bf16x8 d = ((const bf16x8*)p11)[off];
    bf16x8 o;
    #pragma unroll
    for (int j = 0; j < 8; ++j)
      o[j] = (__bf16)((((float)a[j] + (float)b[j]) + ((float)c[j] + (float)d[j])) * inv);
    *(bf16x8*)&Als[rl][c8*8] = o;
  }
  __syncthreads();
  f32x4 acc[4][4] = {};
  for (int t = 0; t < 16; ++t){
    bf16x8 af[4];
    #pragma unroll
    for (int mf2 = 0; mf2 < 4; ++mf2) af[mf2] = *(const bf16x8*)&Als[mf2*16 + lr][t*32 + lg*8];
    #pragma unroll
    for (int nf2 = 0; nf2 < 4; ++nf2){
      bf16x8 bfr = *(const bf16x8*)&W1t[(size_t)(w*64 + nf2*16 + lr)*DMODEL + t*32 + lg*8];
      #pragma unroll
      for (int mf2 = 0; mf2 < 4; ++mf2)
        acc[mf2][nf2] = mfma16x16x32(af[mf2], bfr, acc[mf2][nf2]);
    }
  }
  float part[4][4] = {};
  #pragma unroll
  for (int nf2 = 0; nf2 < 4; ++nf2){
    int col = w*64 + nf2*16 + lr;
    float bb = b1[col], w2v = W2[col];
    #pragma unroll
    for (int mf2 = 0; mf2 < 4; ++mf2)
      #pragma unroll
      for (int r = 0; r < 4; ++r){
        float h = acc[mf2][nf2][r] + bb;
        h = h > 0.0f ? h : 0.0f;
        part[mf2][r] += h * w2v;
      }
  }
  #pragma unroll
  for (int mf2 = 0; mf2 < 4; ++mf2)
    #pragma unroll
    for (int r = 0; r < 4; ++r)
      #pragma unroll
      for (int dl = 1; dl < 16; dl <<= 1)
        part[mf2][r] += __shfl_xor(part[mf2][r], dl);
  if (lr == 0){
    #pragma unroll
    for (int mf2 = 0; mf2 < 4; ++mf2)
      #pragma unroll
      for (int r = 0; r < 4; ++r)
        red[w][mf2*16 + lg*4 + r] = part[mf2][r];
  }
  __syncthreads();
  if (tid < 64)
    out[m0 + tid] = red[0][tid] + red[1][tid] + red[2][tid] + red[3][tid] + b2[0];
}

// ---------------- launcher ----------------
extern "C" void kernel_launch(void* const* d_in, const int* in_sizes, int n_in,
                              void* d_out, int out_size, void* d_ws, size_t ws_size,
                              hipStream_t stream)
{
  const float* x  = (const float*)d_in[0];
  const float* Wq = (const float*)d_in[1];
  const float* bq = (const float*)d_in[2];
  const float* Wk = (const float*)d_in[3];
  const float* bk = (const float*)d_in[4];
  const float* Wv = (const float*)d_in[5];
  const float* bv = (const float*)d_in[6];
  const float* W1 = (const float*)d_in[7];
  const float* b1 = (const float*)d_in[8];
  const float* W2 = (const float*)d_in[9];
  const float* b2 = (const float*)d_in[10];
  float* out = (float*)d_out;
  char* ws = (char*)d_ws;
  // workspace layout
  __bf16* xb   = (__bf16*)(ws + 0);          // 16 MB (dead after V GEMM)
  __bf16* qkb  = (__bf16*)(ws + 16777216);   // 16 MB [8192][1024] rows [q|k]
  __bf16* vtb  = (__bf16*)(ws + 33554432);   // 8 MB  V^T [512][8192]
  __bf16* wqkt = (__bf16*)(ws + 50331648);   // 2 MB  [Wq^T ; Wk^T]
  __bf16* wvt  = (__bf16*)(ws + 52428800);   // 1 MB
  __bf16* w1t  = (__bf16*)(ws + 53477376);   // 0.25 MB -> ends 53739520
  float*  rs   = (float*)(ws + 53739520);    // 32 KB
  float*  bqk  = (float*)(ws + 53772288);    // 4 KB
  float*  rsp  = (float*)(ws + 54525952);    // 4 MB  [128][8192] partial row sums
  __bf16* Ph   = (__bf16*)(ws + 58720256);   // 64 MB  P half [8192][4096]
  __bf16* vpp  = (__bf16*)(ws + 58720256);   // V-proj partials (Ph region, early)
  // PV split-K partials (dead-region reuse)
  __bf16* p00  = (__bf16*)(ws + 0);          // xb region
  __bf16* p01  = (__bf16*)(ws + 8388608);
  __bf16* p10  = (__bf16*)(ws + 16777216);   // qkb region (dead after pexp1)
  __bf16* p11  = (__bf16*)(ws + 25165824);

  k_cvt<<<2048, 256, 0, stream>>>(x, xb, N_TOK*INDIM/4);
  k_tcvt<<<512, 256, 0, stream>>>(Wq, wqkt, INDIM, DMODEL);
  k_tcvt<<<512, 256, 0, stream>>>(Wk, wqkt + (size_t)DMODEL*INDIM, INDIM, DMODEL);
  k_tcvt<<<512, 256, 0, stream>>>(Wv, wvt, INDIM, DMODEL);
  k_tcvt<<<256, 256, 0, stream>>>(W1, w1t, DMODEL, DMODEL/2);
  k_bias2<<<4, 256, 0, stream>>>(bq, bk, bqk);

  // fused Q|K projection
  k_gemm<0,0,0><<<dim3(64, 8), 256, 0, stream>>>(xb, wqkt, bqk, qkb,
      N_TOK, 2*DMODEL, INDIM, INDIM, INDIM, 2*DMODEL, 0.f, nullptr, 0);
  // V^T split-K + combine
  k_gemm<3,0,0><<<dim3(4, 64, 2), 256, 0, stream>>>(wvt, xb, nullptr, vpp,
      DMODEL, N_TOK, INDIM/2, INDIM, INDIM, N_TOK, 0.f, nullptr, 0);
  k_vcomb<<<DMODEL*N_TOK/8/256, 256, 0, stream>>>(vpp, bv, vtb);

  const float scale = 0.04419417382415922f;  // 1/sqrt(512)
  const __bf16* Qm = qkb;            // lda 1024
  const __bf16* Km = qkb + DMODEL;   // ldb 1024
  // ---- half 0 ----
  k_gemm<2,1,1><<<2048, 256, 0, stream>>>(Qm, Km, nullptr, Ph,
      N_TOK, NHALF, DMODEL, 2*DMODEL, 2*DMODEL, NHALF, scale, rsp, 0);
  k_gemm<3,2,0><<<512, 256, 0, stream>>>(Ph, vtb, nullptr, p00,
      N_TOK, DMODEL, NHALF/2, NHALF, N_TOK, DMODEL, 0.f, nullptr, 0);
  // ---- half 1 ----
  k_gemm<2,1,1><<<2048, 256, 0, stream>>>(Qm, Km + (size_t)NHALF*2*DMODEL, nullptr, Ph,
      N_TOK, NHALF, DMODEL, 2*DMODEL, 2*DMODEL, NHALF, scale, rsp, 64);
  k_gemm<3,2,0><<<512, 256, 0, stream>>>(Ph, vtb + NHALF, nullptr, p10,
      N_TOK, DMODEL, NHALF/2, NHALF, N_TOK, DMODEL, 0.f, nullptr, 0);

  k_rsum<<<32, 256, 0, stream>>>(rsp, rs);
  k_mlp<<<N_TOK/64, 256, 0, stream>>>(p00, p01, p10, p11, rs,
      w1t, b1, W2, b2, out);

  (void)in_sizes; (void)n_in; (void)out_size; (void)ws_size;
}

// Round 17
// 271.097 us; speedup vs baseline: 1.1171x; 1.1171x over previous
//
#include <hip/hip_runtime.h>
#include <hip/hip_bf16.h>
#include <cstdint>
#include <cstddef>

typedef float  f32x4  __attribute__((ext_vector_type(4)));
typedef __bf16 bf16x8 __attribute__((ext_vector_type(8)));
typedef __bf16 bf16x4 __attribute__((ext_vector_type(4)));

#define N_TOK  8192
#define INDIM  1024
#define DMODEL 512
#define NHALF  4096   // key-split half for P materialization

__device__ __forceinline__ f32x4 mfma16x16x32(bf16x8 a, bf16x8 b, f32x4 c){
  return __builtin_amdgcn_mfma_f32_16x16x32_bf16(a, b, c, 0, 0, 0);
}

__device__ __forceinline__ void async_copy16(void* lds, const void* g){
  __builtin_amdgcn_global_load_lds((__attribute__((address_space(1))) void*)g,
                                   (__attribute__((address_space(3))) void*)lds,
                                   16, 0, 0);
}

// ---------------- convert / transpose / bias-concat ----------------
__global__ void k_cvt(const float* __restrict__ in, __bf16* __restrict__ out, int n4){
  int stride = gridDim.x * blockDim.x;
  for (int i = blockIdx.x * blockDim.x + threadIdx.x; i < n4; i += stride){
    f32x4 v = ((const f32x4*)in)[i];
    bf16x4 o;
    o[0]=(__bf16)v[0]; o[1]=(__bf16)v[1]; o[2]=(__bf16)v[2]; o[3]=(__bf16)v[3];
    ((bf16x4*)out)[i] = o;
  }
}

__global__ void k_tcvt(const float* __restrict__ W, __bf16* __restrict__ Wt, int Kd, int Nd){
  int total = Kd * Nd;
  int stride = gridDim.x * blockDim.x;
  for (int i = blockIdx.x * blockDim.x + threadIdx.x; i < total; i += stride){
    int k = i / Nd, n = i - k * Nd;
    Wt[(size_t)n * Kd + k] = (__bf16)W[i];
  }
}

__global__ void k_bias2(const float* __restrict__ a, const float* __restrict__ b,
                        float* __restrict__ o){
  int idx = blockIdx.x * 256 + threadIdx.x;   // 0..1023
  o[idx] = (idx < 512) ? a[idx] : b[idx - 512];
}

// ---------------- generalized GEMM: C[M,N] = A[M,K-chunk] @ Bt^T ------------
// 128x128 tile, BK=64, double-buffered, 2-phase (stage-next issued before
// compute, one __syncthreads/iter). LDS [128][64] with 16B-slot XOR swizzle
// (s ^= row&7): linear gload_lds dest + pre-swizzled global source +
// swizzled ds_read (rule-21 both-sides involution). 32 MFMA / sync pair.
// EPI: 0 = +bias[col]; 2 = exp(scale*acc); 3 = plain.
// MAP: 0 = (x=m, y=n, z=K-chunk); 1 = xcd-chunked m (grid 2048);
//      2 = z = xcd>>2, n innermost (grid 512).
// RSUM: fused per-(colblock,row) partial row sums from acc (deterministic).
template<int EPI, int MAP, int RSUM>
__global__ __launch_bounds__(256) void k_gemm(
    const __bf16* __restrict__ A, const __bf16* __restrict__ Bt,
    const float* __restrict__ bias, __bf16* __restrict__ C,
    int M, int N, int K, int lda, int ldb, int ldc, float scale,
    float* __restrict__ rsp, int rbase)
{
  __shared__ __bf16 Als[2][128*64];   // 32 KB
  __shared__ __bf16 Bls[2][128*64];   // 32 KB
  const int tid = threadIdx.x;
  const int w = tid >> 6, l = tid & 63;
  const int lr = l & 15, lg = l >> 4;
  const int wr = w >> 1, wc = w & 1;
  int m0, n0, kz, zsel;
  if (MAP == 0){
    m0 = blockIdx.x * 128; n0 = blockIdx.y * 128; zsel = blockIdx.z; kz = zsel * K;
  } else if (MAP == 1){
    int lin = blockIdx.x, xcd = lin & 7, idx = lin >> 3;
    m0 = (xcd*8 + (idx & 7)) * 128; n0 = (idx >> 3) * 128; zsel = 0; kz = 0;
  } else {
    int lin = blockIdx.x, xcd = lin & 7, i = lin >> 3;
    zsel = xcd >> 2; kz = zsel * K;
    m0 = ((xcd & 3)*16 + (i >> 2)) * 128; n0 = (i & 3) * 128;
  }
  // stage addressing: dest byte f = ro*4096 + w*1024 + l*16
  //   row = ro*32 + w*8 + (l>>3), slot = l&7; source col pre-swizzled:
  //   colelems = ((l&7) ^ (l>>3)) * 8   (row&7 == l>>3)
  const int srow = w*8 + (l >> 3);
  const int scol = ((l & 7) ^ (l >> 3)) * 8;

  auto stage = [&](int b, int kk){
    #pragma unroll
    for (int ro = 0; ro < 4; ++ro)
      async_copy16((char*)&Als[b][0] + ro*4096 + w*1024,
                   A  + (size_t)(m0 + ro*32 + srow) * lda + kk + scol);
    #pragma unroll
    for (int ro = 0; ro < 4; ++ro)
      async_copy16((char*)&Bls[b][0] + ro*4096 + w*1024,
                   Bt + (size_t)(n0 + ro*32 + srow) * ldb + kk + scol);
  };

  f32x4 acc[4][4] = {};
  const int nt = K >> 6;
  stage(0, kz);
  __syncthreads();
  const int r7 = lr & 7;
  for (int t = 0; t < nt; ++t){
    const int cur = t & 1;
    if (t + 1 < nt) stage(cur ^ 1, kz + (t+1)*64);   // issue-early
    #pragma unroll
    for (int kk = 0; kk < 2; ++kk){
      const int cs = ((kk*4 + lg) ^ r7) * 8;   // swizzled 16B slot
      bf16x8 af[4], bfv[4];
      #pragma unroll
      for (int mf = 0; mf < 4; ++mf)
        af[mf]  = *(const bf16x8*)&Als[cur][(wr*64 + mf*16 + lr)*64 + cs];
      #pragma unroll
      for (int nf = 0; nf < 4; ++nf)
        bfv[nf] = *(const bf16x8*)&Bls[cur][(wc*64 + nf*16 + lr)*64 + cs];
      #pragma unroll
      for (int mf = 0; mf < 4; ++mf)
        #pragma unroll
        for (int nf = 0; nf < 4; ++nf)
          acc[mf][nf] = mfma16x16x32(af[mf], bfv[nf], acc[mf][nf]);
    }
    __syncthreads();   // drains stage (issued a full phase earlier) + reads
  }
  // ---- epilogue: direct scattered stores + optional fused row sums ----
  __bf16* Cd = C + (size_t)zsel * (size_t)M * ldc;
  float rsp4[4][4];
  #pragma unroll
  for (int mf = 0; mf < 4; ++mf)
    #pragma unroll
    for (int r = 0; r < 4; ++r) rsp4[mf][r] = 0.0f;
  #pragma unroll
  for (int mf = 0; mf < 4; ++mf)
    #pragma unroll
    for (int nf = 0; nf < 4; ++nf)
      #pragma unroll
      for (int r = 0; r < 4; ++r){
        int row = m0 + wr*64 + mf*16 + lg*4 + r;
        int col = n0 + wc*64 + nf*16 + lr;
        float v = acc[mf][nf][r];
        if (EPI == 0) v += bias[col];
        if (EPI == 2) v = __expf(v * scale);
        Cd[(size_t)row * ldc + col] = (__bf16)v;
        if (RSUM) rsp4[mf][r] += v;
      }
  if (RSUM){
    #pragma unroll
    for (int mf = 0; mf < 4; ++mf)
      #pragma unroll
      for (int r = 0; r < 4; ++r)
        #pragma unroll
        for (int dl = 1; dl < 16; dl <<= 1)
          rsp4[mf][r] += __shfl_xor(rsp4[mf][r], dl);
    if (lr == 0){
      int cb = rbase + (n0 >> 6) + wc;
      #pragma unroll
      for (int mf = 0; mf < 4; ++mf)
        #pragma unroll
        for (int r = 0; r < 4; ++r)
          rsp[(size_t)cb * N_TOK + m0 + wr*64 + mf*16 + lg*4 + r] = rsp4[mf][r];
    }
  }
}

// ---------------- rs[row] = sum of 128 rsp partials ----------------
__global__ __launch_bounds__(256) void k_rsum(
    const float* __restrict__ rsp, float* __restrict__ rs)
{
  int row = blockIdx.x * 256 + threadIdx.x;   // 8192
  float s = 0.0f;
  #pragma unroll 8
  for (int j = 0; j < 128; ++j) s += rsp[(size_t)j * N_TOK + row];
  rs[row] = s;
}

// ---------------- V-projection split-K combine: vtb = p0 + p1 + bv[row] -----
__global__ __launch_bounds__(256) void k_vcomb(
    const __bf16* __restrict__ p, const float* __restrict__ bv,
    __bf16* __restrict__ vtb)
{
  int idx = blockIdx.x * 256 + threadIdx.x;   // 512*8192/8
  int row = idx >> 10;
  float b = bv[row];
  bf16x8 a = ((const bf16x8*)p)[idx];
  bf16x8 c = ((const bf16x8*)(p + (size_t)DMODEL * N_TOK))[idx];
  bf16x8 o;
  #pragma unroll
  for (int i = 0; i < 8; ++i)
    o[i] = (__bf16)((float)a[i] + (float)c[i] + b);
  ((bf16x8*)vtb)[idx] = o;
}

// ---------------- MLP head (fused 4-partial combine + GEMM + reduce) --------
__global__ __launch_bounds__(256) void k_mlp(
    const __bf16* __restrict__ p00, const __bf16* __restrict__ p01,
    const __bf16* __restrict__ p10, const __bf16* __restrict__ p11,
    const float* __restrict__ rs, const __bf16* __restrict__ W1t,
    const float* __restrict__ b1, const float* __restrict__ W2,
    const float* __restrict__ b2, float* __restrict__ out)
{
  __shared__ __bf16 Als[64][512];
  __shared__ float  red[4][64];
  const int tid = threadIdx.x;
  const int w = tid >> 6, l = tid & 63;
  const int lr = l & 15, lg = l >> 4;
  const int m0 = blockIdx.x * 64;
  #pragma unroll
  for (int i = 0; i < 16; ++i){
    int chunk = i*256 + tid;            // 0..4095
    int rl = chunk >> 6, c8 = chunk & 63;
    size_t off = (size_t)(m0 + rl) * 64 + c8;
    float inv = 1.0f / rs[m0 + rl];
    bf16x8 a = ((const bf16x8*)p00)[off];
    bf16x8 b = ((const bf16x8*)p01)[off];
    bf16x8 c = ((const bf16x8*)p10)[off];
    bf16x8 d = ((const bf16x8*)p11)[off];
    bf16x8 o;
    #pragma unroll
    for (int j = 0; j < 8; ++j)
      o[j] = (__bf16)((((float)a[j] + (float)b[j]) + ((float)c[j] + (float)d[j])) * inv);
    *(bf16x8*)&Als[rl][c8*8] = o;
  }
  __syncthreads();
  f32x4 acc[4][4] = {};
  for (int t = 0; t < 16; ++t){
    bf16x8 af[4];
    #pragma unroll
    for (int mf2 = 0; mf2 < 4; ++mf2) af[mf2] = *(const bf16x8*)&Als[mf2*16 + lr][t*32 + lg*8];
    #pragma unroll
    for (int nf2 = 0; nf2 < 4; ++nf2){
      bf16x8 bfr = *(const bf16x8*)&W1t[(size_t)(w*64 + nf2*16 + lr)*DMODEL + t*32 + lg*8];
      #pragma unroll
      for (int mf2 = 0; mf2 < 4; ++mf2)
        acc[mf2][nf2] = mfma16x16x32(af[mf2], bfr, acc[mf2][nf2]);
    }
  }
  float part[4][4] = {};
  #pragma unroll
  for (int nf2 = 0; nf2 < 4; ++nf2){
    int col = w*64 + nf2*16 + lr;
    float bb = b1[col], w2v = W2[col];
    #pragma unroll
    for (int mf2 = 0; mf2 < 4; ++mf2)
      #pragma unroll
      for (int r = 0; r < 4; ++r){
        float h = acc[mf2][nf2][r] + bb;
        h = h > 0.0f ? h : 0.0f;
        part[mf2][r] += h * w2v;
      }
  }
  #pragma unroll
  for (int mf2 = 0; mf2 < 4; ++mf2)
    #pragma unroll
    for (int r = 0; r < 4; ++r)
      #pragma unroll
      for (int dl = 1; dl < 16; dl <<= 1)
        part[mf2][r] += __shfl_xor(part[mf2][r], dl);
  if (lr == 0){
    #pragma unroll
    for (int mf2 = 0; mf2 < 4; ++mf2)
      #pragma unroll
      for (int r = 0; r < 4; ++r)
        red[w][mf2*16 + lg*4 + r] = part[mf2][r];
  }
  __syncthreads();
  if (tid < 64)
    out[m0 + tid] = red[0][tid] + red[1][tid] + red[2][tid] + red[3][tid] + b2[0];
}

// ---------------- launcher ----------------
extern "C" void kernel_launch(void* const* d_in, const int* in_sizes, int n_in,
                              void* d_out, int out_size, void* d_ws, size_t ws_size,
                              hipStream_t stream)
{
  const float* x  = (const float*)d_in[0];
  const float* Wq = (const float*)d_in[1];
  const float* bq = (const float*)d_in[2];
  const float* Wk = (const float*)d_in[3];
  const float* bk = (const float*)d_in[4];
  const float* Wv = (const float*)d_in[5];
  const float* bv = (const float*)d_in[6];
  const float* W1 = (const float*)d_in[7];
  const float* b1 = (const float*)d_in[8];
  const float* W2 = (const float*)d_in[9];
  const float* b2 = (const float*)d_in[10];
  float* out = (float*)d_out;
  char* ws = (char*)d_ws;
  // workspace layout
  __bf16* xb   = (__bf16*)(ws + 0);          // 16 MB (dead after V GEMM)
  __bf16* qkb  = (__bf16*)(ws + 16777216);   // 16 MB [8192][1024] rows [q|k]
  __bf16* vtb  = (__bf16*)(ws + 33554432);   // 8 MB  V^T [512][8192]
  __bf16* wqkt = (__bf16*)(ws + 50331648);   // 2 MB  [Wq^T ; Wk^T]
  __bf16* wvt  = (__bf16*)(ws + 52428800);   // 1 MB
  __bf16* w1t  = (__bf16*)(ws + 53477376);   // 0.25 MB -> ends 53739520
  float*  rs   = (float*)(ws + 53739520);    // 32 KB
  float*  bqk  = (float*)(ws + 53772288);    // 4 KB
  float*  rsp  = (float*)(ws + 54525952);    // 4 MB  [128][8192] partial row sums
  __bf16* Ph   = (__bf16*)(ws + 58720256);   // 64 MB  P half [8192][4096]
  __bf16* vpp  = (__bf16*)(ws + 58720256);   // V-proj partials (Ph region, early)
  // PV split-K partials (dead-region reuse)
  __bf16* p00  = (__bf16*)(ws + 0);          // xb region
  __bf16* p01  = (__bf16*)(ws + 8388608);
  __bf16* p10  = (__bf16*)(ws + 16777216);   // qkb region (dead after pexp1)
  __bf16* p11  = (__bf16*)(ws + 25165824);

  k_cvt<<<2048, 256, 0, stream>>>(x, xb, N_TOK*INDIM/4);
  k_tcvt<<<512, 256, 0, stream>>>(Wq, wqkt, INDIM, DMODEL);
  k_tcvt<<<512, 256, 0, stream>>>(Wk, wqkt + (size_t)DMODEL*INDIM, INDIM, DMODEL);
  k_tcvt<<<512, 256, 0, stream>>>(Wv, wvt, INDIM, DMODEL);
  k_tcvt<<<256, 256, 0, stream>>>(W1, w1t, DMODEL, DMODEL/2);
  k_bias2<<<4, 256, 0, stream>>>(bq, bk, bqk);

  // fused Q|K projection
  k_gemm<0,0,0><<<dim3(64, 8), 256, 0, stream>>>(xb, wqkt, bqk, qkb,
      N_TOK, 2*DMODEL, INDIM, INDIM, INDIM, 2*DMODEL, 0.f, nullptr, 0);
  // V^T split-K + combine
  k_gemm<3,0,0><<<dim3(4, 64, 2), 256, 0, stream>>>(wvt, xb, nullptr, vpp,
      DMODEL, N_TOK, INDIM/2, INDIM, INDIM, N_TOK, 0.f, nullptr, 0);
  k_vcomb<<<DMODEL*N_TOK/8/256, 256, 0, stream>>>(vpp, bv, vtb);

  const float scale = 0.04419417382415922f;  // 1/sqrt(512)
  const __bf16* Qm = qkb;            // lda 1024
  const __bf16* Km = qkb + DMODEL;   // ldb 1024
  // ---- half 0 ----
  k_gemm<2,1,1><<<2048, 256, 0, stream>>>(Qm, Km, nullptr, Ph,
      N_TOK, NHALF, DMODEL, 2*DMODEL, 2*DMODEL, NHALF, scale, rsp, 0);
  k_gemm<3,2,0><<<512, 256, 0, stream>>>(Ph, vtb, nullptr, p00,
      N_TOK, DMODEL, NHALF/2, NHALF, N_TOK, DMODEL, 0.f, nullptr, 0);
  // ---- half 1 ----
  k_gemm<2,1,1><<<2048, 256, 0, stream>>>(Qm, Km + (size_t)NHALF*2*DMODEL, nullptr, Ph,
      N_TOK, NHALF, DMODEL, 2*DMODEL, 2*DMODEL, NHALF, scale, rsp, 64);
  k_gemm<3,2,0><<<512, 256, 0, stream>>>(Ph, vtb + NHALF, nullptr, p10,
      N_TOK, DMODEL, NHALF/2, NHALF, N_TOK, DMODEL, 0.f, nullptr, 0);

  k_rsum<<<32, 256, 0, stream>>>(rsp, rs);
  k_mlp<<<N_TOK/64, 256, 0, stream>>>(p00, p01, p10, p11, rs,
      w1t, b1, W2, b2, out);

  (void)in_sizes; (void)n_in; (void)out_size; (void)ws_size;
}